// Round 13
// baseline (13.192 us; speedup 1.0000x reference)
//
#include <hip/hip_runtime.h>
#include <math.h>

#define NTH 256
#define G   4
#define RPB (NTH*G)   // rows per block

__device__ __forceinline__ float frcp(float x) { return __builtin_amdgcn_rcpf(x); }

__device__ __forceinline__ float get_comp(const float4& v, int c) {
    switch (c) { case 0: return v.x; case 1: return v.y; case 2: return v.z; default: return v.w; }
}

__device__ __forceinline__ float iou_loss_one(const float b1[7], const float b2[7], float w)
{
    // z overlap + volumes
    float zmax = fminf(b1[2]+0.5f*b1[5], b2[2]+0.5f*b2[5]);
    float zmin = fmaxf(b1[2]-0.5f*b1[5], b2[2]-0.5f*b2[5]);
    float dz = fmaxf(zmax - zmin, 0.0f);
    float v1 = b1[3]*b1[4]*b1[5];
    float v2 = b2[3]*b2[4]*b2[5];

    float hw1 = 0.5f*b1[3], hl1 = 0.5f*b1[4];
    float hw2 = 0.5f*b2[3], hl2 = 0.5f*b2[4];

    // Frame1: rotate by -a1 about box1 center. Box1 -> axis-aligned at origin.
    float ca1 = __cosf(b1[6]), sa1 = __sinf(b1[6]);
    float ca2 = __cosf(b2[6]), sa2 = __sinf(b2[6]);
    float ct = ca2*ca1 + sa2*sa1;    // cos(a2-a1)
    float st = sa2*ca1 - ca2*sa1;    // sin(a2-a1)
    float ox = b2[0] - b1[0], oy = b2[1] - b1[1];
    float Ox =  ox*ca1 + oy*sa1;
    float Oy =  oy*ca1 - ox*sa1;

    float ux = hw2*ct, uy = hw2*st;
    float vx = -hl2*st, vy = hl2*ct;

    float wx_ = ux+vx, wy_ = uy+vy, zx_ = ux-vx, zy_ = uy-vy;
    float q0x = Ox+wx_, q0y = Oy+wy_;
    float q1x = Ox-zx_, q1y = Oy-zy_;
    float q2x = Ox-wx_, q2y = Oy-wy_;
    float q3x = Ox+zx_, q3y = Oy+zy_;

    float i2ux = frcp(ux+ux), i2uy = frcp(uy+uy);
    float i2vx = frcp(vx+vx), i2vy = frcp(vy+vy);

    float s2 = 0.0f;

    #define CLIP_Q(AX,AY,DX,DY,IUX,IUY)  {                                  \
        float ta = (-hw1 - (AX))*(IUX), tb = (hw1 - (AX))*(IUX);            \
        float tc = (-hl1 - (AY))*(IUY), td = (hl1 - (AY))*(IUY);            \
        float tlu = fminf(ta,tb), thu = fmaxf(ta,tb);                       \
        float tlv = fminf(tc,td), thv = fmaxf(tc,td);                       \
        float tin  = fmaxf(fmaxf(tlu,tlv), 0.0f);                           \
        float tout = fminf(fminf(thu,thv), 1.0f);                           \
        bool ok = tin < tout;                                               \
        float Apx = (AX) + tin*(DX),  Apy = (AY) + tin*(DY);                \
        float Bpx = (AX) + tout*(DX), Bpy = (AY) + tout*(DY);               \
        float cr = Apx*Bpy - Apy*Bpx;                                       \
        s2 += ok ? cr : 0.0f; }

    CLIP_Q(q0x,q0y, -(ux+ux), -(uy+uy), -i2ux, -i2uy)
    CLIP_Q(q1x,q1y, -(vx+vx), -(vy+vy), -i2vx, -i2vy)
    CLIP_Q(q2x,q2y,  (ux+ux),  (uy+uy),  i2ux,  i2uy)
    CLIP_Q(q3x,q3y,  (vx+vx),  (vy+vy),  i2vx,  i2vy)
    #undef CLIP_Q

    float Au = (hw1+hw1)*ct, Av = (hw1+hw1)*st;
    float Cu = (hl1+hl1)*st, Cv = (hl1+hl1)*ct;
    float iAu = frcp(Au), iAv = frcp(Av), iCu = frcp(Cu), iCv = frcp(Cv);

    float rx = hw1 - Ox, ry = hl1 - Oy;
    float p0u = rx*ct + ry*st,  p0v = ry*ct - rx*st;
    float p1u = p0u - Au, p1v = p0v + Av;
    float p2u = p1u - Cu, p2v = p1v - Cv;
    float p3u = p0u - Cu, p3v = p0v - Cv;

    float sdt = 0.0f;
    #define CLIP_P(PU,PV,IDU,IDV) {                                         \
        float ta = (-hw2 - (PU))*(IDU), tb = (hw2 - (PU))*(IDU);            \
        float tc = (-hl2 - (PV))*(IDV), td = (hl2 - (PV))*(IDV);            \
        float tlu = fminf(ta,tb), thu = fmaxf(ta,tb);                       \
        float tlv = fminf(tc,td), thv = fmaxf(tc,td);                       \
        float tin  = fmaxf(fmaxf(tlu,tlv), 0.0f);                           \
        float tout = fminf(fminf(thu,thv), 1.0f);                           \
        float dt = tout - tin;                                              \
        sdt += (dt > 0.0f) ? dt : 0.0f; }

    CLIP_P(p0u,p0v, -iAu,  iAv)
    CLIP_P(p1u,p1v, -iCu, -iCv)
    CLIP_P(p2u,p2v,  iAu, -iAv)
    CLIP_P(p3u,p3v,  iCu,  iCv)
    #undef CLIP_P

    s2 += (hw1+hw1)*hl1*sdt;

    float area = 0.5f*fabsf(s2);
    float inter_vol = area * dz;
    float iou = inter_vol * frcp(v1 + v2 - inter_vol + 1e-8f);
    return (1.0f - iou) * w;
}

__global__ __launch_bounds__(NTH) void iou_loss_kernel(
    const float* __restrict__ pred, const float* __restrict__ target,
    const float* __restrict__ weight, float* __restrict__ partial, int n)
{
    const int tid = threadIdx.x;
    const int t = blockIdx.x * NTH + tid;   // thread's 4-row group index
    const int i4 = t * 4;
    float loss = 0.0f;

    if (i4 + 3 < n) {
        // widest read path: 4 consecutive rows = 28 floats = 7 dwordx4 per array
        float4 p[7], q[7];
        const float4* pp = reinterpret_cast<const float4*>(pred + (size_t)i4*7);
        const float4* qq = reinterpret_cast<const float4*>(target + (size_t)i4*7);
        #pragma unroll
        for (int k = 0; k < 7; ++k) { p[k] = pp[k]; q[k] = qq[k]; }
        float4 wv = *reinterpret_cast<const float4*>(weight + i4);

        #pragma unroll
        for (int r = 0; r < 4; ++r) {
            float b1[7], b2[7];
            #pragma unroll
            for (int j = 0; j < 7; ++j) {
                int f = r*7 + j;
                b1[j] = get_comp(p[f >> 2], f & 3);
                b2[j] = get_comp(q[f >> 2], f & 3);
            }
            loss += iou_loss_one(b1, b2, get_comp(wv, r));
        }
    } else {
        for (int r = 0; r < 4; ++r) {
            int i = i4 + r;
            if (i < n) {
                float b1[7], b2[7];
                #pragma unroll
                for (int j = 0; j < 7; ++j) { b1[j] = pred[i*7+j]; b2[j] = target[i*7+j]; }
                loss += iou_loss_one(b1, b2, weight[i]);
            }
        }
    }

    // block reduction -> per-block partial (no atomics, no fences)
    #pragma unroll
    for (int off = 32; off > 0; off >>= 1) loss += __shfl_down(loss, off, 64);
    __shared__ float wsum[NTH/64];
    int lane = tid & 63, wid = tid >> 6;
    if (lane == 0) wsum[wid] = loss;
    __syncthreads();
    if (tid == 0) {
        float s = 0.0f;
        #pragma unroll
        for (int w = 0; w < NTH/64; ++w) s += wsum[w];
        partial[blockIdx.x] = s;
    }
}

#define RTH 128
__global__ __launch_bounds__(RTH) void reduce_kernel(
    const float* __restrict__ partial, int nb, float* __restrict__ out, double inv_n)
{
    double s = 0.0;
    for (int j = threadIdx.x; j < nb; j += RTH) s += (double)partial[j];
    #pragma unroll
    for (int off = 32; off > 0; off >>= 1) s += __shfl_down(s, off, 64);
    __shared__ double wsum[RTH/64];
    int lane = threadIdx.x & 63, wid = threadIdx.x >> 6;
    if (lane == 0) wsum[wid] = s;
    __syncthreads();
    if (threadIdx.x == 0) {
        double tot = 0.0;
        #pragma unroll
        for (int w = 0; w < RTH/64; ++w) tot += wsum[w];
        out[0] = (float)(tot * inv_n);
    }
}

extern "C" void kernel_launch(void* const* d_in, const int* in_sizes, int n_in,
                              void* d_out, int out_size, void* d_ws, size_t ws_size,
                              hipStream_t stream) {
    const float* pred   = (const float*)d_in[0];
    const float* target = (const float*)d_in[1];
    const float* weight = (const float*)d_in[2];
    int n = in_sizes[2];
    float* partial = (float*)d_ws;
    int nblocks = (n + RPB - 1) / RPB;
    hipLaunchKernelGGL(iou_loss_kernel, dim3(nblocks), dim3(NTH), 0, stream,
                       pred, target, weight, partial, n);
    hipLaunchKernelGGL(reduce_kernel, dim3(1), dim3(RTH), 0, stream,
                       partial, nblocks, (float*)d_out, 1.0 / (double)n);
}